// Round 13
// baseline (323.033 us; speedup 1.0000x reference)
//
#include <hip/hip_runtime.h>
#include <hip/hip_bf16.h>
#include <cmath>

#define N_TOK 16384
#define D_DIM 2048
#define H_DIM 1024
#define E_DIM 64

typedef _Float16 half8 __attribute__((ext_vector_type(8)));
typedef float floatx4 __attribute__((ext_vector_type(4)));

#define GLOAD_LDS(gp, lp)                                                      \
  __builtin_amdgcn_global_load_lds(                                            \
      (const __attribute__((address_space(1))) unsigned int*)(gp),             \
      (__attribute__((address_space(3))) unsigned int*)(lp), 16, 0, 0)

// ---------------------------------------------------------------------------
// Transpose + split W1 [2048k][1024c] -> whT/wlT [1024c][2048k] f16.
// ---------------------------------------------------------------------------
__global__ __launch_bounds__(256) void splitT_w1_kernel(
    const float* __restrict__ W1, _Float16* __restrict__ whT,
    _Float16* __restrict__ wlT) {
  __shared__ float ls[64][65];
  const int k0 = blockIdx.x * 64;
  const int c0 = blockIdx.y * 64;
  const int t = threadIdx.x;
  const int tr = t >> 6;
  const int tc = t & 63;
#pragma unroll
  for (int i = 0; i < 16; i++) {
    int k = tr * 16 + i;
    ls[k][tc] = W1[(size_t)(k0 + k) * H_DIM + c0 + tc];
  }
  __syncthreads();
#pragma unroll
  for (int i = 0; i < 16; i++) {
    int c = tr * 16 + i;
    float v = ls[tc][c];
    _Float16 hv = (_Float16)v;
    _Float16 lv = (_Float16)(v - (float)hv);
    whT[(size_t)(c0 + c) * D_DIM + k0 + tc] = hv;
    wlT[(size_t)(c0 + c) * D_DIM + k0 + tc] = lv;
  }
}

// ---------------------------------------------------------------------------
// GEMM1: h = x @ W1, f16 hi/lo split computed AT FRAG-READ TIME.
// A staged as RAW FP32 via global_load_lds (32KB/tile, slot^(row&7) swizzle);
// B staged as pre-split f16 hi/lo via global_load_lds (R3/R12 layout).
// 16x16x32 MFMA, 256x256 tile, BK=32, 512 thr (8 waves 2Mx4N), 128KB dbuf.
// Loop: issue 8 gloads (T+1) -> frag-read+cvt+MFMA -> vmcnt(0) (pre-landed)
// -> lgkmcnt(0) -> s_barrier. One barrier per tile.
// ---------------------------------------------------------------------------
__global__ __launch_bounds__(512, 2) void gemm1_mfma_kernel(
    const float* __restrict__ x, const _Float16* __restrict__ whT,
    const _Float16* __restrict__ wlT, float* __restrict__ h) {
  extern __shared__ __align__(16) char smem[];  // 2 x 64KB: [A f32|Bh|Bl]

  const int t = threadIdx.x;
  const int wave = t >> 6;
  const int lane = t & 63;

  const int bid = blockIdx.x;
  const int swz = (bid & 7) * 32 + (bid >> 3);  // XCD swizzle (256 = 8*32)
  const int by = swz >> 2, bx = swz & 3;
  const int row0 = by * 256, col0 = bx * 256;
  const int wr = wave >> 2, wc = wave & 3;  // wave tile 128x64

  floatx4 acc[8][4];
#pragma unroll
  for (int m = 0; m < 8; m++)
#pragma unroll
    for (int n = 0; n < 4; n++) acc[m][n] = (floatx4){0.f, 0.f, 0.f, 0.f};

  // ---- A staging: fp32 tile [256 rows][32 k] = 32KB, 8x16B slots/row,
  //      source slot pre-swizzled by row&7 (dest linear, rule 21) ----
  int ldsAoff[4];
  size_t gaoff[4];
#pragma unroll
  for (int q = 0; q < 4; q++) {
    const int o = q * 8192 + t * 16;       // byte offset in A array
    const int row = o >> 7;                // 128B per row (32 f32)
    const int ss = ((o >> 4) & 7) ^ (row & 7);
    ldsAoff[q] = q * 8192 + wave * 1024;   // wave-uniform dest base
    gaoff[q] = (size_t)(row0 + row) * D_DIM + ss * 4;
  }

  // ---- B staging (R3/R12-verified): f16 hi/lo, 64B rows, 4 slots ----
  int ldsBoff[2];
  size_t gboff[2];
#pragma unroll
  for (int q = 0; q < 2; q++) {
    const int o = q * 8192 + t * 16;
    const int row = o >> 6;
    const int ss = ((o >> 4) & 3) ^ ((row >> 1) & 3);
    ldsBoff[q] = q * 8192 + wave * 1024;
    gboff[q] = (size_t)(col0 + row) * D_DIM + ss * 8;
  }

  const int kg = lane >> 4;
  const int fr = lane & 15;

  // ---- fragment addrs ----
  // A fp32: frag = 8 f32 at row r, k=kg*8..+8 -> 2x16B at slots 2kg, 2kg+1.
  int afr[8][2];
#pragma unroll
  for (int m = 0; m < 8; m++) {
    const int r = wr * 128 + m * 16 + fr;
#pragma unroll
    for (int hh = 0; hh < 2; hh++)
      afr[m][hh] = r * 128 + (((2 * kg + hh) ^ (r & 7)) << 4);
  }
  // B f16 (R12-verified, 0 conflicts)
  int bfr[4];
#pragma unroll
  for (int n = 0; n < 4; n++) {
    const int c = wc * 64 + n * 16 + fr;
    bfr[n] = c * 64 + ((kg ^ ((c >> 1) & 3)) << 4);
  }

#define GLD_A(T)                                                               \
  do {                                                                         \
    const size_t kk = (size_t)(T) * 32;                                        \
    char* db = smem + ((T) & 1) * 65536;                                       \
    GLOAD_LDS(x + gaoff[0] + kk, db + ldsAoff[0]);                             \
    GLOAD_LDS(x + gaoff[1] + kk, db + ldsAoff[1]);                             \
    GLOAD_LDS(x + gaoff[2] + kk, db + ldsAoff[2]);                             \
    GLOAD_LDS(x + gaoff[3] + kk, db + ldsAoff[3]);                             \
  } while (0)

#define GLD_B(T)                                                               \
  do {                                                                         \
    const size_t kk = (size_t)(T) * 32;                                        \
    char* db = smem + ((T) & 1) * 65536;                                       \
    GLOAD_LDS(whT + gboff[0] + kk, db + 32768 + ldsBoff[0]);                   \
    GLOAD_LDS(whT + gboff[1] + kk, db + 32768 + ldsBoff[1]);                   \
    GLOAD_LDS(wlT + gboff[0] + kk, db + 49152 + ldsBoff[0]);                   \
    GLOAD_LDS(wlT + gboff[1] + kk, db + 49152 + ldsBoff[1]);                   \
  } while (0)

  // STG: 0 = steady (stage T+1), 1 = tail (no staging)
#define BODY(T, STG)                                                           \
  do {                                                                         \
    const char* cb = smem + ((T) & 1) * 65536;                                 \
    if ((STG) == 0) {                                                          \
      GLD_A((T) + 1);                                                          \
      GLD_B((T) + 1);                                                          \
    }                                                                          \
    __builtin_amdgcn_sched_barrier(0);                                         \
    half8 bh[4], bl[4];                                                        \
    _Pragma("unroll") for (int n = 0; n < 4; n++) {                            \
      bh[n] = *(const half8*)(cb + 32768 + bfr[n]);                            \
      bl[n] = *(const half8*)(cb + 49152 + bfr[n]);                            \
    }                                                                          \
    _Pragma("unroll") for (int m = 0; m < 8; m++) {                            \
      float4 f0 = *(const float4*)(cb + afr[m][0]);                            \
      float4 f1 = *(const float4*)(cb + afr[m][1]);                            \
      float fj[8] = {f0.x, f0.y, f0.z, f0.w, f1.x, f1.y, f1.z, f1.w};          \
      half8 ah, al;                                                            \
      _Pragma("unroll") for (int j = 0; j < 8; j++) {                          \
        _Float16 hv = (_Float16)fj[j];                                         \
        ah[j] = hv;                                                            \
        al[j] = (_Float16)(fj[j] - (float)hv);                                 \
      }                                                                        \
      __builtin_amdgcn_s_setprio(1);                                           \
      _Pragma("unroll") for (int n = 0; n < 4; n++) {                          \
        acc[m][n] = __builtin_amdgcn_mfma_f32_16x16x32_f16(ah, bh[n],          \
                                                           acc[m][n], 0, 0, 0);\
        acc[m][n] = __builtin_amdgcn_mfma_f32_16x16x32_f16(ah, bl[n],          \
                                                           acc[m][n], 0, 0, 0);\
        acc[m][n] = __builtin_amdgcn_mfma_f32_16x16x32_f16(al, bh[n],          \
                                                           acc[m][n], 0, 0, 0);\
      }                                                                        \
      __builtin_amdgcn_s_setprio(0);                                           \
    }                                                                          \
    __builtin_amdgcn_sched_barrier(0);                                         \
    if ((STG) == 0) {                                                          \
      asm volatile("s_waitcnt vmcnt(0)" ::: "memory"); /* pre-landed */        \
      asm volatile("s_waitcnt lgkmcnt(0)" ::: "memory");                       \
      __builtin_amdgcn_s_barrier();                                            \
      __builtin_amdgcn_sched_barrier(0);                                       \
    }                                                                          \
  } while (0)

  // ---- Prologue: stage tile 0 ----
  GLD_A(0);
  GLD_B(0);
  asm volatile("s_waitcnt vmcnt(0)" ::: "memory");
  __builtin_amdgcn_s_barrier();
  __builtin_amdgcn_sched_barrier(0);

#pragma unroll 1
  for (int T = 0; T < 63; ++T) {
    BODY(T, 0);
  }
  BODY(63, 1);

#undef GLD_A
#undef GLD_B
#undef BODY

  // Epilogue: C/D layout col=lane&15, row=(lane>>4)*4+j  [m89-verified]
  const int rj = (lane >> 4) * 4;
#pragma unroll
  for (int m = 0; m < 8; m++) {
    const int rbase = row0 + wr * 128 + m * 16 + rj;
#pragma unroll
    for (int n = 0; n < 4; n++) {
      const int c = col0 + wc * 64 + n * 16 + fr;
#pragma unroll
      for (int j = 0; j < 4; j++) {
        h[(size_t)(rbase + j) * H_DIM + c] = acc[m][n][j];
      }
    }
  }
}

// ---------------------------------------------------------------------------
// Kernel 2: per 8 tokens: +b1, LayerNorm, exact GELU, logits = g @ W2 + b2,
// softmax, top-2 (selected on logits; lower-index tie-break), renorm weights.
// ---------------------------------------------------------------------------
__device__ __forceinline__ float gelu_exact(float v) {
  return 0.5f * v * (1.0f + erff(v * 0.70710678118654752f));
}

__global__ __launch_bounds__(256) void router_kernel(
    const float* __restrict__ hbuf, const float* __restrict__ b1,
    const float* __restrict__ gamma, const float* __restrict__ beta,
    const float* __restrict__ W2, const float* __restrict__ b2,
    float* __restrict__ out) {
  __shared__ float g[8][H_DIM];
  __shared__ float w2s[128][E_DIM];
  __shared__ float lg[8][E_DIM];

  const int t = threadIdx.x;
  const int tok0 = blockIdx.x * 8;

  const int tk = t >> 5;
  const int l32 = t & 31;
  float vals[32];
  {
    const float* hr = hbuf + (size_t)(tok0 + tk) * H_DIM;
    float s = 0.f, s2 = 0.f;
#pragma unroll
    for (int q = 0; q < 8; q++) {
      const int j = q * 128 + l32 * 4;
      float4 v = *(const float4*)(hr + j);
      float4 bb = *(const float4*)(b1 + j);
      v.x += bb.x; v.y += bb.y; v.z += bb.z; v.w += bb.w;
      vals[q * 4 + 0] = v.x; vals[q * 4 + 1] = v.y;
      vals[q * 4 + 2] = v.z; vals[q * 4 + 3] = v.w;
      s += v.x + v.y + v.z + v.w;
      s2 += v.x * v.x + v.y * v.y + v.z * v.z + v.w * v.w;
    }
#pragma unroll
    for (int off = 16; off; off >>= 1) {
      s += __shfl_xor(s, off, 32);
      s2 += __shfl_xor(s2, off, 32);
    }
    const float mean = s * (1.f / 1024.f);
    const float var = s2 * (1.f / 1024.f) - mean * mean;
    const float rstd = rsqrtf(var + 1e-5f);
#pragma unroll
    for (int q = 0; q < 8; q++) {
      const int j = q * 128 + l32 * 4;
      float4 gm = *(const float4*)(gamma + j);
      float4 bt = *(const float4*)(beta + j);
      float4 o;
      o.x = gelu_exact((vals[q * 4 + 0] - mean) * rstd * gm.x + bt.x);
      o.y = gelu_exact((vals[q * 4 + 1] - mean) * rstd * gm.y + bt.y);
      o.z = gelu_exact((vals[q * 4 + 2] - mean) * rstd * gm.z + bt.z);
      o.w = gelu_exact((vals[q * 4 + 3] - mean) * rstd * gm.w + bt.w);
      *(float4*)&g[tk][j] = o;
    }
  }

  {
    float* lgf = &lg[0][0];
    lgf[t] = b2[t & 63];
    lgf[t + 256] = b2[t & 63];
  }

  const int seg = t >> 6;
  const int cell = t & 63;
  const int tp = cell >> 4;
  const int e0 = (cell & 15) * 4;

  float acc0[4] = {0.f, 0.f, 0.f, 0.f};
  float acc1[4] = {0.f, 0.f, 0.f, 0.f};

  for (int c = 0; c < 8; c++) {
    __syncthreads();
#pragma unroll
    for (int q = 0; q < 8; q++) {
      const int idx = q * 1024 + t * 4;
      *(float4*)(&w2s[0][0] + idx) = *(const float4*)(W2 + c * 8192 + idx);
    }
    __syncthreads();
#pragma unroll
    for (int q = 0; q < 8; q++) {
      const int i = seg * 32 + q * 4;
      float4 g0 = *(const float4*)&g[2 * tp][c * 128 + i];
      float4 g1 = *(const float4*)&g[2 * tp + 1][c * 128 + i];
      float4 w0 = *(const float4*)&w2s[i + 0][e0];
      float4 w1 = *(const float4*)&w2s[i + 1][e0];
      float4 w2v = *(const float4*)&w2s[i + 2][e0];
      float4 w3 = *(const float4*)&w2s[i + 3][e0];
      acc0[0] = fmaf(g0.x, w0.x, acc0[0]); acc0[1] = fmaf(g0.x, w0.y, acc0[1]);
      acc0[2] = fmaf(g0.x, w0.z, acc0[2]); acc0[3] = fmaf(g0.x, w0.w, acc0[3]);
      acc0[0] = fmaf(g0.y, w1.x, acc0[0]); acc0[1] = fmaf(g0.y, w1.y, acc0[1]);
      acc0[2] = fmaf(g0.y, w1.z, acc0[2]); acc0[3] = fmaf(g0.y, w1.w, acc0[3]);
      acc0[0] = fmaf(g0.z, w2v.x, acc0[0]); acc0[1] = fmaf(g0.z, w2v.y, acc0[1]);
      acc0[2] = fmaf(g0.z, w2v.z, acc0[2]); acc0[3] = fmaf(g0.z, w2v.w, acc0[3]);
      acc0[0] = fmaf(g0.w, w3.x, acc0[0]); acc0[1] = fmaf(g0.w, w3.y, acc0[1]);
      acc0[2] = fmaf(g0.w, w3.z, acc0[2]); acc0[3] = fmaf(g0.w, w3.w, acc0[3]);
      acc1[0] = fmaf(g1.x, w0.x, acc1[0]); acc1[1] = fmaf(g1.x, w0.y, acc1[1]);
      acc1[2] = fmaf(g1.x, w0.z, acc1[2]); acc1[3] = fmaf(g1.x, w0.w, acc1[3]);
      acc1[0] = fmaf(g1.y, w1.x, acc1[0]); acc1[1] = fmaf(g1.y, w1.y, acc1[1]);
      acc1[2] = fmaf(g1.y, w1.z, acc1[2]); acc1[3] = fmaf(g1.y, w1.w, acc1[3]);
      acc1[0] = fmaf(g1.z, w2v.x, acc1[0]); acc1[1] = fmaf(g1.z, w2v.y, acc1[1]);
      acc1[2] = fmaf(g1.z, w2v.z, acc1[2]); acc1[3] = fmaf(g1.z, w2v.w, acc1[3]);
      acc1[0] = fmaf(g1.w, w3.x, acc1[0]); acc1[1] = fmaf(g1.w, w3.y, acc1[1]);
      acc1[2] = fmaf(g1.w, w3.z, acc1[2]); acc1[3] = fmaf(g1.w, w3.w, acc1[3]);
    }
  }
#pragma unroll
  for (int j = 0; j < 4; j++) {
    atomicAdd(&lg[2 * tp][e0 + j], acc0[j]);
    atomicAdd(&lg[2 * tp + 1][e0 + j], acc1[j]);
  }
  __syncthreads();

  float* out_idx = out;
  float* out_w = out + 32768;
  float* out_logits = out + 65536;

  const int wv = t >> 6;
  const int lane = t & 63;
#pragma unroll
  for (int tt = 0; tt < 2; tt++) {
    const int tok = wv * 2 + tt;
    const int n = tok0 + tok;
    const float L = lg[tok][lane];
    float m = L;
#pragma unroll
    for (int off = 32; off; off >>= 1) m = fmaxf(m, __shfl_xor(m, off));
    const float ex = expf(L - m);
    float sum = ex;
#pragma unroll
    for (int off = 32; off; off >>= 1) sum += __shfl_xor(sum, off);

    // top-2 on logits (same ordering as on softmax probs; monotonic)
    float v1 = L; int i1 = lane;
#pragma unroll
    for (int off = 32; off; off >>= 1) {
      float ov = __shfl_xor(v1, off);
      int oi = __shfl_xor(i1, off);
      if (ov > v1 || (ov == v1 && oi < i1)) { v1 = ov; i1 = oi; }
    }
    float v2 = (lane == i1) ? -1e30f : L; int i2 = lane;
#pragma unroll
    for (int off = 32; off; off >>= 1) {
      float ov = __shfl_xor(v2, off);
      int oi = __shfl_xor(i2, off);
      if (ov > v2 || (ov == v2 && oi < i2)) { v2 = ov; i2 = oi; }
    }

    out_logits[(size_t)n * 64 + lane] = L;
    if (lane == 0) {
      const float p1 = expf(v1 - m) / sum;
      const float p2 = expf(v2 - m) / sum;
      const float dn = p1 + p2 + 1e-9f;
      out_idx[n * 2 + 0] = (float)i1;
      out_idx[n * 2 + 1] = (float)i2;
      out_w[n * 2 + 0] = p1 / dn;
      out_w[n * 2 + 1] = p2 / dn;
    }
  }
}

extern "C" void kernel_launch(void* const* d_in, const int* in_sizes, int n_in,
                              void* d_out, int out_size, void* d_ws, size_t ws_size,
                              hipStream_t stream) {
  const float* x = (const float*)d_in[0];
  const float* W1 = (const float*)d_in[1];
  const float* b1 = (const float*)d_in[2];
  const float* gamma = (const float*)d_in[3];
  const float* beta = (const float*)d_in[4];
  const float* W2 = (const float*)d_in[5];
  const float* b2 = (const float*)d_in[6];
  float* out = (float*)d_out;

  char* ws = (char*)d_ws;
  _Float16* whT = (_Float16*)ws;                 // 4 MiB
  _Float16* wlT = (_Float16*)(ws + 4194304);     // 4 MiB
  float* hbuf = (float*)(ws + 8388608);          // 64 MiB (total 72 MiB)

  (void)hipFuncSetAttribute((const void*)gemm1_mfma_kernel,
                            hipFuncAttributeMaxDynamicSharedMemorySize,
                            131072);

  splitT_w1_kernel<<<dim3(D_DIM / 64, H_DIM / 64), 256, 0, stream>>>(W1, whT, wlT);

  gemm1_mfma_kernel<<<256, 512, 131072, stream>>>(x, whT, wlT, hbuf);

  router_kernel<<<N_TOK / 8, 256, 0, stream>>>(hbuf, b1, gamma, beta, W2, b2, out);
}

// Round 14
// 263.909 us; speedup vs baseline: 1.2240x; 1.2240x over previous
//
#include <hip/hip_runtime.h>
#include <hip/hip_bf16.h>
#include <cmath>

#define N_TOK 16384
#define D_DIM 2048
#define H_DIM 1024
#define E_DIM 64

typedef _Float16 half8 __attribute__((ext_vector_type(8)));
typedef float floatx4 __attribute__((ext_vector_type(4)));

#define GLOAD_LDS(gp, lp)                                                      \
  __builtin_amdgcn_global_load_lds(                                            \
      (const __attribute__((address_space(1))) unsigned int*)(gp),             \
      (__attribute__((address_space(3))) unsigned int*)(lp), 16, 0, 0)

// ---------------------------------------------------------------------------
// Transpose + split W1 [2048k][1024c] -> whT/wlT [1024c][2048k] f16.
// ---------------------------------------------------------------------------
__global__ __launch_bounds__(256) void splitT_w1_kernel(
    const float* __restrict__ W1, _Float16* __restrict__ whT,
    _Float16* __restrict__ wlT) {
  __shared__ float ls[64][65];
  const int k0 = blockIdx.x * 64;
  const int c0 = blockIdx.y * 64;
  const int t = threadIdx.x;
  const int tr = t >> 6;
  const int tc = t & 63;
#pragma unroll
  for (int i = 0; i < 16; i++) {
    int k = tr * 16 + i;
    ls[k][tc] = W1[(size_t)(k0 + k) * H_DIM + c0 + tc];
  }
  __syncthreads();
#pragma unroll
  for (int i = 0; i < 16; i++) {
    int c = tr * 16 + i;
    float v = ls[tc][c];
    _Float16 hv = (_Float16)v;
    _Float16 lv = (_Float16)(v - (float)hv);
    whT[(size_t)(c0 + c) * D_DIM + k0 + tc] = hv;
    wlT[(size_t)(c0 + c) * D_DIM + k0 + tc] = lv;
  }
}

// ---------------------------------------------------------------------------
// Pack + split W2 [1024k][64e] -> MFMA-B-fragment-order hi/lo f16:
// p[( (s*4+ng)*64 + lane )*8 + j] = W2[s*32 + (lane>>4)*8 + j][ng*16+(lane&15)]
// so a wave's B-frag load for kstep s, expert-group ng is 1KB contiguous.
// ---------------------------------------------------------------------------
__global__ __launch_bounds__(256) void pack_w2_kernel(
    const float* __restrict__ W2, _Float16* __restrict__ pW2h,
    _Float16* __restrict__ pW2l) {
  const int s = blockIdx.x;  // 32 ksteps
  const int ng = threadIdx.x >> 6;
  const int lane = threadIdx.x & 63;
  const int kg = lane >> 4, fr = lane & 15;
  half8 hh, ll;
#pragma unroll
  for (int j = 0; j < 8; j++) {
    const float v = W2[(size_t)(s * 32 + kg * 8 + j) * E_DIM + ng * 16 + fr];
    const _Float16 hv = (_Float16)v;
    hh[j] = hv;
    ll[j] = (_Float16)(v - (float)hv);
  }
  const size_t idx = (((size_t)s * 4 + ng) * 64 + lane) * 8;
  *(half8*)(pW2h + idx) = hh;
  *(half8*)(pW2l + idx) = ll;
}

// ---------------------------------------------------------------------------
// GEMM1 (R12-verified, verbatim): h = x @ W1, f16 hi/lo split, 16x16x32 MFMA,
// 256x256 tile, BK=32, 512 thr, counted-vmcnt pipeline, 0-conflict layouts.
// ---------------------------------------------------------------------------
__global__ __launch_bounds__(512, 2) void gemm1_mfma_kernel(
    const float* __restrict__ x, const _Float16* __restrict__ whT,
    const _Float16* __restrict__ wlT, float* __restrict__ h) {
  extern __shared__ __align__(16) char smem[];  // 2 x 64KB: Ah|Al|Bh|Bl

  const int t = threadIdx.x;
  const int wave = t >> 6;
  const int lane = t & 63;

  const int bid = blockIdx.x;
  const int swz = (bid & 7) * 32 + (bid >> 3);  // XCD swizzle (256 = 8*32)
  const int by = swz >> 2, bx = swz & 3;
  const int row0 = by * 256, col0 = bx * 256;
  const int wr = wave >> 2, wc = wave & 3;  // wave tile 128x64

  floatx4 acc[8][4];
#pragma unroll
  for (int m = 0; m < 8; m++)
#pragma unroll
    for (int n = 0; n < 4; n++) acc[m][n] = (floatx4){0.f, 0.f, 0.f, 0.f};

  int awaddr[2];
  size_t gaoff[2];
#pragma unroll
  for (int q = 0; q < 2; q++) {
    const int u = q * 512 + t;
    const int arow = u >> 2;
    const int aslot = u & 3;
    awaddr[q] = arow * 64 + ((aslot ^ ((arow >> 1) & 3)) << 4);
    gaoff[q] = (size_t)(row0 + arow) * D_DIM + aslot * 8;
  }

  int ldsoff[2];
  size_t gboff[2];
#pragma unroll
  for (int q = 0; q < 2; q++) {
    const int o = q * 8192 + t * 16;
    const int row = o >> 6;
    const int ss = ((o >> 4) & 3) ^ ((row >> 1) & 3);
    ldsoff[q] = q * 8192 + wave * 1024;
    gboff[q] = (size_t)(col0 + row) * D_DIM + ss * 8;
  }

  const int kg = lane >> 4;
  const int fr = lane & 15;

  int afr[8], bfr[4];
#pragma unroll
  for (int m = 0; m < 8; m++) {
    const int r = wr * 128 + m * 16 + fr;
    afr[m] = r * 64 + ((kg ^ ((r >> 1) & 3)) << 4);
  }
#pragma unroll
  for (int n = 0; n < 4; n++) {
    const int c = wc * 64 + n * 16 + fr;
    bfr[n] = c * 64 + ((kg ^ ((c >> 1) & 3)) << 4);
  }

  float4 av[2][2];

#define LOAD_A(T)                                                              \
  do {                                                                         \
    const size_t kk = (size_t)(T) * 32;                                        \
    av[0][0] = *(const float4*)(x + gaoff[0] + kk);                            \
    av[0][1] = *(const float4*)(x + gaoff[0] + kk + 4);                        \
    av[1][0] = *(const float4*)(x + gaoff[1] + kk);                            \
    av[1][1] = *(const float4*)(x + gaoff[1] + kk + 4);                        \
  } while (0)

#define WRITE_A(B)                                                             \
  do {                                                                         \
    char* lb = smem + (B) * 65536;                                             \
    _Pragma("unroll") for (int q = 0; q < 2; q++) {                            \
      float vs[8] = {av[q][0].x, av[q][0].y, av[q][0].z, av[q][0].w,           \
                     av[q][1].x, av[q][1].y, av[q][1].z, av[q][1].w};          \
      half8 hh, ll;                                                            \
      _Pragma("unroll") for (int j = 0; j < 8; j++) {                          \
        _Float16 hv = (_Float16)vs[j];                                         \
        hh[j] = hv;                                                            \
        ll[j] = (_Float16)(vs[j] - (float)hv);                                 \
      }                                                                        \
      *(half8*)(lb + awaddr[q]) = hh;                                          \
      *(half8*)(lb + 16384 + awaddr[q]) = ll;                                  \
    }                                                                          \
  } while (0)

#define GLD_B(T)                                                               \
  do {                                                                         \
    const size_t kk = (size_t)(T) * 32;                                        \
    char* db = smem + ((T) & 1) * 65536;                                       \
    GLOAD_LDS(whT + gboff[0] + kk, db + 32768 + ldsoff[0]);                    \
    GLOAD_LDS(whT + gboff[1] + kk, db + 32768 + ldsoff[1]);                    \
    GLOAD_LDS(wlT + gboff[0] + kk, db + 49152 + ldsoff[0]);                    \
    GLOAD_LDS(wlT + gboff[1] + kk, db + 49152 + ldsoff[1]);                    \
  } while (0)

#define BODY(T, STG)                                                           \
  do {                                                                         \
    const char* cb = smem + ((T) & 1) * 65536;                                 \
    if ((STG) < 2) GLD_B((T) + 1);                                             \
    __builtin_amdgcn_sched_barrier(0);                                         \
    half8 bh[4], bl[4];                                                        \
    _Pragma("unroll") for (int n = 0; n < 4; n++) {                            \
      bh[n] = *(const half8*)(cb + 32768 + bfr[n]);                            \
      bl[n] = *(const half8*)(cb + 49152 + bfr[n]);                            \
    }                                                                          \
    _Pragma("unroll") for (int m = 0; m < 8; m++) {                            \
      half8 ah = *(const half8*)(cb + afr[m]);                                 \
      half8 al = *(const half8*)(cb + 16384 + afr[m]);                         \
      __builtin_amdgcn_s_setprio(1);                                           \
      _Pragma("unroll") for (int n = 0; n < 4; n++) {                          \
        acc[m][n] = __builtin_amdgcn_mfma_f32_16x16x32_f16(ah, bh[n],          \
                                                           acc[m][n], 0, 0, 0);\
        acc[m][n] = __builtin_amdgcn_mfma_f32_16x16x32_f16(ah, bl[n],          \
                                                           acc[m][n], 0, 0, 0);\
        acc[m][n] = __builtin_amdgcn_mfma_f32_16x16x32_f16(al, bh[n],          \
                                                           acc[m][n], 0, 0, 0);\
      }                                                                        \
      __builtin_amdgcn_s_setprio(0);                                           \
    }                                                                          \
    __builtin_amdgcn_sched_barrier(0);                                         \
    if ((STG) < 2) {                                                           \
      WRITE_A(((T) + 1) & 1);                                                  \
      if ((STG) == 0) {                                                        \
        LOAD_A((T) + 2);                                                       \
        __builtin_amdgcn_sched_barrier(0);                                     \
        asm volatile("s_waitcnt vmcnt(4)" ::: "memory");                       \
      } else {                                                                 \
        __builtin_amdgcn_sched_barrier(0);                                     \
        asm volatile("s_waitcnt vmcnt(0)" ::: "memory");                       \
      }                                                                        \
      asm volatile("s_waitcnt lgkmcnt(0)" ::: "memory");                       \
      __builtin_amdgcn_s_barrier();                                            \
      __builtin_amdgcn_sched_barrier(0);                                       \
    }                                                                          \
  } while (0)

  LOAD_A(0);
  GLD_B(0);
  WRITE_A(0);
  LOAD_A(1);
  asm volatile("s_waitcnt vmcnt(4)" ::: "memory");
  asm volatile("s_waitcnt lgkmcnt(0)" ::: "memory");
  __builtin_amdgcn_s_barrier();
  __builtin_amdgcn_sched_barrier(0);

#pragma unroll 1
  for (int T = 0; T < 62; ++T) {
    BODY(T, 0);
  }
  BODY(62, 1);
  BODY(63, 2);

#undef LOAD_A
#undef WRITE_A
#undef GLD_B
#undef BODY

  const int rj = (lane >> 4) * 4;
#pragma unroll
  for (int m = 0; m < 8; m++) {
    const int rbase = row0 + wr * 128 + m * 16 + rj;
#pragma unroll
    for (int n = 0; n < 4; n++) {
      const int c = col0 + wc * 64 + n * 16 + fr;
#pragma unroll
      for (int j = 0; j < 4; j++) {
        h[(size_t)(rbase + j) * H_DIM + c] = acc[m][n][j];
      }
    }
  }
}

// ---------------------------------------------------------------------------
// Router v2 (MFMA): 16 tokens/block, 256 thr (4 waves).
// Phase 1: LN+GELU (16 lanes/token), g -> LDS as hi/lo f16 in 32 chunks of
//          [16 tok][64B] with R12's verified slot^((tok>>1)&3) swizzle.
// Phase 2: logits = g @ W2 via 16x16x32 MFMA; wave w owns experts w*16..+15;
//          B-frags read directly from fragment-packed pW2h/pW2l (L2).
// Phase 3: +b2, softmax, top-2 on logits (lower-index tie-break), renorm.
// LDS: gh 32KB | gl 32KB | lg 4KB = 68.6KB dynamic -> 2 blocks/CU.
// ---------------------------------------------------------------------------
__device__ __forceinline__ float gelu_exact(float v) {
  return 0.5f * v * (1.0f + erff(v * 0.70710678118654752f));
}

__global__ __launch_bounds__(256) void router_kernel(
    const float* __restrict__ hbuf, const float* __restrict__ b1,
    const float* __restrict__ gamma, const float* __restrict__ beta,
    const _Float16* __restrict__ pW2h, const _Float16* __restrict__ pW2l,
    const float* __restrict__ b2, float* __restrict__ out) {
  extern __shared__ __align__(16) char rsm[];
  char* gh = rsm;                    // 32KB
  char* gl = rsm + 32768;            // 32KB
  float* lg = (float*)(rsm + 65536); // 16 x 64 fp32 = 4KB

  const int t = threadIdx.x;
  const int tok0 = blockIdx.x * 16;

  // ---- Phase 1: LN + GELU, 16 lanes per token, 8-contiguous-elem units ----
  const int tk = t >> 4;    // token 0..15
  const int l16 = t & 15;
  {
    const float* hr = hbuf + (size_t)(tok0 + tk) * H_DIM;
    float vals[64];
    float s = 0.f, s2 = 0.f;
#pragma unroll
    for (int q2 = 0; q2 < 8; q2++) {
      const int j = q2 * 128 + l16 * 8;
      float4 v0 = *(const float4*)(hr + j);
      float4 v1 = *(const float4*)(hr + j + 4);
      float4 b0 = *(const float4*)(b1 + j);
      float4 b1v = *(const float4*)(b1 + j + 4);
      v0.x += b0.x; v0.y += b0.y; v0.z += b0.z; v0.w += b0.w;
      v1.x += b1v.x; v1.y += b1v.y; v1.z += b1v.z; v1.w += b1v.w;
      vals[q2 * 8 + 0] = v0.x; vals[q2 * 8 + 1] = v0.y;
      vals[q2 * 8 + 2] = v0.z; vals[q2 * 8 + 3] = v0.w;
      vals[q2 * 8 + 4] = v1.x; vals[q2 * 8 + 5] = v1.y;
      vals[q2 * 8 + 6] = v1.z; vals[q2 * 8 + 7] = v1.w;
      s += v0.x + v0.y + v0.z + v0.w + v1.x + v1.y + v1.z + v1.w;
      s2 += v0.x * v0.x + v0.y * v0.y + v0.z * v0.z + v0.w * v0.w +
            v1.x * v1.x + v1.y * v1.y + v1.z * v1.z + v1.w * v1.w;
    }
#pragma unroll
    for (int off = 8; off; off >>= 1) {
      s += __shfl_xor(s, off, 16);
      s2 += __shfl_xor(s2, off, 16);
    }
    const float mean = s * (1.f / 1024.f);
    const float var = s2 * (1.f / 1024.f) - mean * mean;
    const float rstd = rsqrtf(var + 1e-5f);
    // write g hi/lo into chunked LDS: chunk sidx = k/32, slot = (k%32)/8
    const int swz = ((tk >> 1) & 3);
#pragma unroll
    for (int q2 = 0; q2 < 8; q2++) {
      const int j = q2 * 128 + l16 * 8;
      half8 hh, ll;
#pragma unroll
      for (int e = 0; e < 8; e++) {
        const int jj = q2 * 8 + e;
        const int col = j + e;
        const float gm = gamma[col], bt = beta[col];
        const float gv = gelu_exact((vals[jj] - mean) * rstd * gm + bt);
        const _Float16 hv = (_Float16)gv;
        hh[e] = hv;
        ll[e] = (_Float16)(gv - (float)hv);
      }
      const int sidx = q2 * 4 + (l16 >> 2);
      const int addr = sidx * 1024 + tk * 64 + (((l16 & 3) ^ swz) << 4);
      *(half8*)(gh + addr) = hh;
      *(half8*)(gl + addr) = ll;
    }
  }
  __syncthreads();

  // ---- Phase 2: logits via MFMA. wave w -> experts w*16..w*16+15 ----
  const int wave = t >> 6;
  const int lane = t & 63;
  const int kg = lane >> 4;
  const int fr = lane & 15;
  {
    floatx4 acc = (floatx4){0.f, 0.f, 0.f, 0.f};
    const int aswz = ((fr >> 1) & 3);
#pragma unroll
    for (int s = 0; s < 32; s++) {
      const int aaddr = s * 1024 + fr * 64 + ((kg ^ aswz) << 4);
      half8 ah = *(const half8*)(gh + aaddr);
      half8 al = *(const half8*)(gl + aaddr);
      const size_t bo = (((size_t)s * 4 + wave) * 64 + lane) * 8;
      half8 bh = *(const half8*)(pW2h + bo);
      half8 bl = *(const half8*)(pW2l + bo);
      acc = __builtin_amdgcn_mfma_f32_16x16x32_f16(ah, bh, acc, 0, 0, 0);
      acc = __builtin_amdgcn_mfma_f32_16x16x32_f16(ah, bl, acc, 0, 0, 0);
      acc = __builtin_amdgcn_mfma_f32_16x16x32_f16(al, bh, acc, 0, 0, 0);
    }
    // C layout: row(token) = kg*4 + j, col(expert-in-group) = fr
#pragma unroll
    for (int j = 0; j < 4; j++) {
      lg[(kg * 4 + j) * E_DIM + wave * 16 + fr] = acc[j];
    }
  }
  __syncthreads();

  // ---- Phase 3: +b2, softmax, top-2, outputs. wave w -> tokens 4w..4w+3 ---
  float* out_idx = out;
  float* out_w = out + 32768;
  float* out_logits = out + 65536;

  const float b2v = b2[lane];
#pragma unroll
  for (int tt = 0; tt < 4; tt++) {
    const int tok = wave * 4 + tt;
    const int n = tok0 + tok;
    const float L = lg[tok * E_DIM + lane] + b2v;
    float m = L;
#pragma unroll
    for (int off = 32; off; off >>= 1) m = fmaxf(m, __shfl_xor(m, off));
    const float ex = expf(L - m);
    float sum = ex;
#pragma unroll
    for (int off = 32; off; off >>= 1) sum += __shfl_xor(sum, off);

    float v1 = L; int i1 = lane;
#pragma unroll
    for (int off = 32; off; off >>= 1) {
      float ov = __shfl_xor(v1, off);
      int oi = __shfl_xor(i1, off);
      if (ov > v1 || (ov == v1 && oi < i1)) { v1 = ov; i1 = oi; }
    }
    float v2 = (lane == i1) ? -1e30f : L; int i2 = lane;
#pragma unroll
    for (int off = 32; off; off >>= 1) {
      float ov = __shfl_xor(v2, off);
      int oi = __shfl_xor(i2, off);
      if (ov > v2 || (ov == v2 && oi < i2)) { v2 = ov; i2 = oi; }
    }

    out_logits[(size_t)n * 64 + lane] = L;
    if (lane == 0) {
      const float p1 = expf(v1 - m) / sum;
      const float p2 = expf(v2 - m) / sum;
      const float dn = p1 + p2 + 1e-9f;
      out_idx[n * 2 + 0] = (float)i1;
      out_idx[n * 2 + 1] = (float)i2;
      out_w[n * 2 + 0] = p1 / dn;
      out_w[n * 2 + 1] = p2 / dn;
    }
  }
}

extern "C" void kernel_launch(void* const* d_in, const int* in_sizes, int n_in,
                              void* d_out, int out_size, void* d_ws, size_t ws_size,
                              hipStream_t stream) {
  const float* x = (const float*)d_in[0];
  const float* W1 = (const float*)d_in[1];
  const float* b1 = (const float*)d_in[2];
  const float* gamma = (const float*)d_in[3];
  const float* beta = (const float*)d_in[4];
  const float* W2 = (const float*)d_in[5];
  const float* b2 = (const float*)d_in[6];
  float* out = (float*)d_out;

  char* ws = (char*)d_ws;
  _Float16* whT = (_Float16*)ws;                  // 4 MiB
  _Float16* wlT = (_Float16*)(ws + 4194304);      // 4 MiB
  float* hbuf = (float*)(ws + 8388608);           // 64 MiB
  _Float16* pW2h = (_Float16*)(ws + 75497472);    // 128 KiB
  _Float16* pW2l = (_Float16*)(ws + 75628544);    // 128 KiB (total ~72.3 MiB)

  (void)hipFuncSetAttribute((const void*)gemm1_mfma_kernel,
                            hipFuncAttributeMaxDynamicSharedMemorySize,
                            131072);
  (void)hipFuncSetAttribute((const void*)router_kernel,
                            hipFuncAttributeMaxDynamicSharedMemorySize,
                            69632);

  splitT_w1_kernel<<<dim3(D_DIM / 64, H_DIM / 64), 256, 0, stream>>>(W1, whT, wlT);
  pack_w2_kernel<<<32, 256, 0, stream>>>(W2, pW2h, pW2l);

  gemm1_mfma_kernel<<<256, 512, 131072, stream>>>(x, whT, wlT, hbuf);

  router_kernel<<<N_TOK / 16, 256, 69632, stream>>>(hbuf, b1, gamma, beta,
                                                    pW2h, pW2l, b2, out);
}